// Round 3
// baseline (546.850 us; speedup 1.0000x reference)
//
#include <hip/hip_runtime.h>
#include <hip/hip_cooperative_groups.h>

#define V_SIZE 50257
#define B_SIZE 256
#define S_LEN  15
#define H_DIM  512
#define NBLK_LG 786   // ceil(50257/64)

typedef __attribute__((ext_vector_type(8))) short bf16x8;
typedef __attribute__((ext_vector_type(4))) float f32x4;

__device__ __forceinline__ unsigned short f2bf(float f) {
    unsigned int u = __float_as_uint(f);
    u += 0x7fffu + ((u >> 16) & 1u);   // RNE
    return (unsigned short)(u >> 16);
}

// ---------------------------------------------------------------------------
// K1: u[b,n] = sum_o h[b,o] * attn_W[o,n]   (fp32 vector; 67 MMAC total)
// ---------------------------------------------------------------------------
__global__ __launch_bounds__(256) void u_kernel(
    const float* __restrict__ hidden, const float* __restrict__ attn_W,
    float* __restrict__ u)
{
    __shared__ float h_s[16][H_DIM];
    const int tid = threadIdx.x;
    const int b0 = blockIdx.y * 16, n0 = blockIdx.x * 32;
    const float4* hv = (const float4*)(hidden + (size_t)b0 * H_DIM);
    float4* hs4 = (float4*)&h_s[0][0];
    #pragma unroll
    for (int i = 0; i < 8; ++i) hs4[tid + i * 256] = hv[tid + i * 256];
    __syncthreads();
    const int n = n0 + (tid & 31);
    const int m = (tid >> 5) * 2;
    float a0 = 0.f, a1 = 0.f;
    #pragma unroll 8
    for (int o = 0; o < H_DIM; ++o) {
        float w = attn_W[(size_t)o * H_DIM + n];
        a0 += h_s[m][o] * w;
        a1 += h_s[m + 1][o] * w;
    }
    u[(size_t)(b0 + m) * H_DIM + n] = a0;
    u[(size_t)(b0 + m + 1) * H_DIM + n] = a1;
}

// ---------------------------------------------------------------------------
// K2: per-b attention + bf16 prep of x=[emb,ctx] and h (enc staged in LDS)
// ---------------------------------------------------------------------------
__global__ __launch_bounds__(256) void attn_kernel(
    const float* __restrict__ hidden, const float* __restrict__ enc,
    const float* __restrict__ u, const int* __restrict__ tokens,
    const float* __restrict__ emb, float* __restrict__ attnw_out,
    unsigned short* __restrict__ x_bf, unsigned short* __restrict__ h_bf)
{
    const int b = blockIdx.x, tid = threadIdx.x;
    __shared__ float e_s[S_LEN][H_DIM];   // 30720 B
    __shared__ float u_s[H_DIM];
    __shared__ float sc_s[S_LEN];
    __shared__ float w_s[S_LEN];
    {
        const float4* ev = (const float4*)(enc + (size_t)b * S_LEN * H_DIM);
        float4* es4 = (float4*)&e_s[0][0];
        #pragma unroll
        for (int i = 0; i < 8; ++i) {
            int idx = i * 256 + tid;
            if (idx < S_LEN * H_DIM / 4) es4[idx] = ev[idx];
        }
    }
    u_s[tid]       = u[(size_t)b * H_DIM + tid];
    u_s[tid + 256] = u[(size_t)b * H_DIM + tid + 256];
    h_bf[(size_t)b * H_DIM + tid]       = f2bf(hidden[(size_t)b * H_DIM + tid]);
    h_bf[(size_t)b * H_DIM + tid + 256] = f2bf(hidden[(size_t)b * H_DIM + tid + 256]);
    const int tok = tokens[b];
    x_bf[(size_t)b * 2 * H_DIM + tid]       = f2bf(emb[(size_t)tok * H_DIM + tid]);
    x_bf[(size_t)b * 2 * H_DIM + tid + 256] = f2bf(emb[(size_t)tok * H_DIM + tid + 256]);
    __syncthreads();
    const int wave = tid >> 6, lane = tid & 63;
    for (int s = wave; s < S_LEN; s += 4) {
        float acc = 0.f;
        #pragma unroll
        for (int k = 0; k < H_DIM / 64; ++k)
            acc += e_s[s][lane + k * 64] * u_s[lane + k * 64];
        #pragma unroll
        for (int off = 32; off; off >>= 1) acc += __shfl_down(acc, off);
        if (lane == 0) sc_s[s] = acc;
    }
    __syncthreads();
    float mx = -1e30f;
    for (int s = 0; s < S_LEN; ++s) mx = fmaxf(mx, sc_s[s]);
    float sum = 0.f;
    for (int s = 0; s < S_LEN; ++s) sum += __expf(sc_s[s] - mx);
    const float inv = 1.f / sum;
    if (tid < S_LEN) {
        float w = __expf(sc_s[tid] - mx) * inv;
        w_s[tid] = w;
        attnw_out[b * S_LEN + tid] = w;
    }
    __syncthreads();
    #pragma unroll
    for (int hh = 0; hh < 2; ++hh) {
        int h = tid + hh * 256;
        float c = 0.f;
        #pragma unroll
        for (int s = 0; s < S_LEN; ++s)
            c += w_s[s] * e_s[s][h];
        x_bf[(size_t)b * 2 * H_DIM + H_DIM + h] = f2bf(c);
    }
}

// ---------------------------------------------------------------------------
// Small NT MFMA GEMM: C = A(bf16) * B(f32->bf16)^T + bias
// ---------------------------------------------------------------------------
struct GemmP {
    const unsigned short* A; const float* B; const float* bias; float* C;
    int N; int K;
};

template<int BM, int BN, int BK, int WR, int WC>
__global__ __launch_bounds__(256) void gemm_nt(GemmP p0, GemmP p1)
{
    GemmP p = (blockIdx.z == 0) ? p0 : p1;
    constexpr int LDA = BK + 8;
    __shared__ __align__(16) unsigned short As[BM][LDA];
    __shared__ __align__(16) unsigned short Bs[BN][LDA];
    const int tid = threadIdx.x;
    const int bn0 = blockIdx.x * BN;
    const int bm0 = blockIdx.y * BM;
    const int wave = tid >> 6, lane = tid & 63;
    const int wm = (wave / WC) * (BM / WR);
    const int wn = (wave % WC) * (BN / WC);
    constexpr int MF = BM / WR / 16, NF = BN / WC / 16;
    const int n16 = lane & 15, quad = lane >> 4;

    f32x4 acc[MF][NF] = {};

    for (int k0 = 0; k0 < p.K; k0 += BK) {
        #pragma unroll
        for (int it = 0; it < BM / 32; ++it) {
            int v = it * 256 + tid;
            int row = v >> 3, seg = v & 7;
            *(uint4*)&As[row][seg * 8] =
                *(const uint4*)(p.A + (size_t)(bm0 + row) * p.K + k0 + seg * 8);
        }
        #pragma unroll
        for (int it = 0; it < BN / 32; ++it) {
            int v = it * 256 + tid;
            int row = v >> 3, seg = v & 7;
            int gv = bn0 + row;
            float4 w0 = make_float4(0, 0, 0, 0), w1 = make_float4(0, 0, 0, 0);
            if (gv < p.N) {
                const float4* src = (const float4*)(p.B + (size_t)gv * p.K + k0 + seg * 8);
                w0 = src[0]; w1 = src[1];
            }
            uint4 pk;
            pk.x = (unsigned)f2bf(w0.x) | ((unsigned)f2bf(w0.y) << 16);
            pk.y = (unsigned)f2bf(w0.z) | ((unsigned)f2bf(w0.w) << 16);
            pk.z = (unsigned)f2bf(w1.x) | ((unsigned)f2bf(w1.y) << 16);
            pk.w = (unsigned)f2bf(w1.z) | ((unsigned)f2bf(w1.w) << 16);
            *(uint4*)&Bs[row][seg * 8] = pk;
        }
        __syncthreads();
        #pragma unroll
        for (int kk = 0; kk < BK; kk += 32) {
            bf16x8 af[MF], bfr[NF];
            #pragma unroll
            for (int i = 0; i < MF; ++i)
                af[i] = *(const bf16x8*)&As[wm + i * 16 + n16][kk + quad * 8];
            #pragma unroll
            for (int j = 0; j < NF; ++j)
                bfr[j] = *(const bf16x8*)&Bs[wn + j * 16 + n16][kk + quad * 8];
            #pragma unroll
            for (int i = 0; i < MF; ++i)
                #pragma unroll
                for (int j = 0; j < NF; ++j)
                    acc[i][j] = __builtin_amdgcn_mfma_f32_16x16x32_bf16(
                        af[i], bfr[j], acc[i][j], 0, 0, 0);
        }
        __syncthreads();
    }
    #pragma unroll
    for (int i = 0; i < MF; ++i) {
        const int r0 = bm0 + wm + i * 16 + quad * 4;
        #pragma unroll
        for (int j = 0; j < NF; ++j) {
            const int c = bn0 + wn + j * 16 + n16;
            if (c < p.N) {
                const float bv = p.bias[c];
                #pragma unroll
                for (int r = 0; r < 4; ++r)
                    p.C[(size_t)(r0 + r) * p.N + c] = acc[i][j][r] + bv;
            }
        }
    }
}

// ---------------------------------------------------------------------------
// COOP logits GEMM + log-softmax, fused via grid.sync (R2 change).
// Phase 1: round-0 GEMM structure (BK=128, 17.4KB LDS, 4 blocks/CU proven
//          86.8us) -> softmax partials to pm/ps. acc stays in VGPRs; NO C
//          write yet.
// grid.sync
// Phase 2: blocks 0..255 combine 786 partials for row b -> lse_g[b].
// grid.sync
// Phase 3: every block writes C = acc + bias - lse ONCE from registers.
// Removes finalize's 103MB logits RMW + one dispatch.
// Residency: 786 blocks, LDS 17.5KB (9/CU), launch_bounds(256,4) caps VGPR
// at 128 (16 waves/CU = 4 blocks/CU -> 1024 >= 786). 
// ---------------------------------------------------------------------------
__global__ __launch_bounds__(256, 4) void gemm_lg_coop(
    const unsigned short* __restrict__ A, const float* __restrict__ B,
    const float* __restrict__ bias, float* __restrict__ C,
    float* __restrict__ pm, float* __restrict__ ps, float* __restrict__ lse_g)
{
    constexpr int BN = 64, BK = 128;
    constexpr int LDB = BK + 8;              // 136 shorts = 272B pitch
    __shared__ __align__(16) unsigned short Bs[BN][LDB];
    __shared__ float red_m[4], red_s[4];
    const int tid = threadIdx.x;
    const int bn0 = blockIdx.x * BN;
    const int wave = tid >> 6, lane = tid & 63;
    const int wm = wave * 64;                 // wave-private 64 A-rows
    const int n16 = lane & 15, quad = lane >> 4;

    f32x4 acc[4][4] = {};
    const unsigned short* arow[4];
    #pragma unroll
    for (int i = 0; i < 4; ++i) arow[i] = A + (size_t)(wm + i * 16 + n16) * H_DIM;

    for (int k0 = 0; k0 < H_DIM; k0 += BK) {
        #pragma unroll
        for (int it = 0; it < 4; ++it) {
            int v = it * 256 + tid;
            int row = v >> 4, seg = v & 15;
            int gv = bn0 + row;
            float4 w0 = make_float4(0, 0, 0, 0), w1 = make_float4(0, 0, 0, 0);
            if (gv < V_SIZE) {
                const float4* src = (const float4*)(B + (size_t)gv * H_DIM + k0 + seg * 8);
                w0 = src[0]; w1 = src[1];
            }
            uint4 pk;
            pk.x = (unsigned)f2bf(w0.x) | ((unsigned)f2bf(w0.y) << 16);
            pk.y = (unsigned)f2bf(w0.z) | ((unsigned)f2bf(w0.w) << 16);
            pk.z = (unsigned)f2bf(w1.x) | ((unsigned)f2bf(w1.y) << 16);
            pk.w = (unsigned)f2bf(w1.z) | ((unsigned)f2bf(w1.w) << 16);
            *(uint4*)&Bs[row][seg * 8] = pk;
        }
        __syncthreads();
        #pragma unroll
        for (int kk = 0; kk < BK; kk += 32) {
            bf16x8 af[4], bfr[4];
            #pragma unroll
            for (int i = 0; i < 4; ++i)
                af[i] = *(const bf16x8*)(arow[i] + k0 + kk + quad * 8);  // global, L2-hit
            #pragma unroll
            for (int j = 0; j < 4; ++j)
                bfr[j] = *(const bf16x8*)&Bs[j * 16 + n16][kk + quad * 8];
            #pragma unroll
            for (int i = 0; i < 4; ++i)
                #pragma unroll
                for (int j = 0; j < 4; ++j)
                    acc[i][j] = __builtin_amdgcn_mfma_f32_16x16x32_bf16(
                        af[i], bfr[j], acc[i][j], 0, 0, 0);
        }
        __syncthreads();
    }

    // ---- phase 1 epilogue: softmax partials only (no C write)
    int cj[4]; float bvv[4]; bool okj[4];
    #pragma unroll
    for (int j = 0; j < 4; ++j) {
        cj[j] = bn0 + j * 16 + n16;
        okj[j] = cj[j] < V_SIZE;
        bvv[j] = okj[j] ? bias[cj[j]] : 0.f;
    }
    #pragma unroll
    for (int i = 0; i < 4; ++i) {
        const int r0 = wm + i * 16 + quad * 4;
        #pragma unroll
        for (int r = 0; r < 4; ++r) {
            float m = -1e30f;
            #pragma unroll
            for (int j = 0; j < 4; ++j)
                if (okj[j]) m = fmaxf(m, acc[i][j][r] + bvv[j]);
            #pragma unroll
            for (int d = 1; d < 16; d <<= 1) m = fmaxf(m, __shfl_xor(m, d));
            float s = 0.f;
            #pragma unroll
            for (int j = 0; j < 4; ++j)
                if (okj[j]) s += __expf(acc[i][j][r] + bvv[j] - m);
            #pragma unroll
            for (int d = 1; d < 16; d <<= 1) s += __shfl_xor(s, d);
            if (n16 == 0) {
                pm[(size_t)blockIdx.x * B_SIZE + r0 + r] = m;
                ps[(size_t)blockIdx.x * B_SIZE + r0 + r] = s;
            }
        }
    }

    cooperative_groups::this_grid().sync();

    // ---- phase 2: blocks 0..255 reduce 786 partials for row b -> lse
    if (blockIdx.x < B_SIZE) {
        const int b = blockIdx.x;
        float m = -1e30f, s = 0.f;
        for (int i = tid; i < NBLK_LG; i += 256) {
            float mm = pm[(size_t)i * B_SIZE + b], ss = ps[(size_t)i * B_SIZE + b];
            float nm = fmaxf(m, mm);
            s = s * __expf(m - nm) + ss * __expf(mm - nm);
            m = nm;
        }
        #pragma unroll
        for (int off = 32; off; off >>= 1) {
            float m2 = __shfl_down(m, off), s2 = __shfl_down(s, off);
            float nm = fmaxf(m, m2);
            s = s * __expf(m - nm) + s2 * __expf(m2 - nm);
            m = nm;
        }
        if (lane == 0) { red_m[wave] = m; red_s[wave] = s; }
        __syncthreads();
        if (tid == 0) {
            float M = red_m[0], S = red_s[0];
            #pragma unroll
            for (int w = 1; w < 4; ++w) {
                float nm = fmaxf(M, red_m[w]);
                S = S * __expf(M - nm) + red_s[w] * __expf(red_m[w] - nm);
                M = nm;
            }
            lse_g[b] = M + logf(S);
        }
    }

    cooperative_groups::this_grid().sync();

    // ---- phase 3: single write of log-probs from registers
    #pragma unroll
    for (int i = 0; i < 4; ++i) {
        const int r0 = wm + i * 16 + quad * 4;
        float ls[4];
        #pragma unroll
        for (int r = 0; r < 4; ++r) ls[r] = lse_g[r0 + r];
        #pragma unroll
        for (int j = 0; j < 4; ++j) if (okj[j]) {
            #pragma unroll
            for (int r = 0; r < 4; ++r)
                C[(size_t)(r0 + r) * V_SIZE + cj[j]] = acc[i][j][r] + bvv[j] - ls[r];
        }
    }
}

// ---------------------------------------------------------------------------
// Fallback (non-coop) logits GEMM: round-0 structure, optional partials.
// ---------------------------------------------------------------------------
template<bool PART>
__global__ __launch_bounds__(256, 4) void gemm_lg(
    const unsigned short* __restrict__ A, const float* __restrict__ B,
    const float* __restrict__ bias, float* __restrict__ C,
    float* __restrict__ pm, float* __restrict__ ps)
{
    constexpr int BN = 64, BK = 128;
    constexpr int LDB = BK + 8;
    __shared__ __align__(16) unsigned short Bs[BN][LDB];
    const int tid = threadIdx.x;
    const int bn0 = blockIdx.x * BN;
    const int wave = tid >> 6, lane = tid & 63;
    const int wm = wave * 64;
    const int n16 = lane & 15, quad = lane >> 4;

    f32x4 acc[4][4] = {};
    const unsigned short* arow[4];
    #pragma unroll
    for (int i = 0; i < 4; ++i) arow[i] = A + (size_t)(wm + i * 16 + n16) * H_DIM;

    for (int k0 = 0; k0 < H_DIM; k0 += BK) {
        #pragma unroll
        for (int it = 0; it < 4; ++it) {
            int v = it * 256 + tid;
            int row = v >> 4, seg = v & 15;
            int gv = bn0 + row;
            float4 w0 = make_float4(0, 0, 0, 0), w1 = make_float4(0, 0, 0, 0);
            if (gv < V_SIZE) {
                const float4* src = (const float4*)(B + (size_t)gv * H_DIM + k0 + seg * 8);
                w0 = src[0]; w1 = src[1];
            }
            uint4 pk;
            pk.x = (unsigned)f2bf(w0.x) | ((unsigned)f2bf(w0.y) << 16);
            pk.y = (unsigned)f2bf(w0.z) | ((unsigned)f2bf(w0.w) << 16);
            pk.z = (unsigned)f2bf(w1.x) | ((unsigned)f2bf(w1.y) << 16);
            pk.w = (unsigned)f2bf(w1.z) | ((unsigned)f2bf(w1.w) << 16);
            *(uint4*)&Bs[row][seg * 8] = pk;
        }
        __syncthreads();
        #pragma unroll
        for (int kk = 0; kk < BK; kk += 32) {
            bf16x8 af[4], bfr[4];
            #pragma unroll
            for (int i = 0; i < 4; ++i)
                af[i] = *(const bf16x8*)(arow[i] + k0 + kk + quad * 8);
            #pragma unroll
            for (int j = 0; j < 4; ++j)
                bfr[j] = *(const bf16x8*)&Bs[j * 16 + n16][kk + quad * 8];
            #pragma unroll
            for (int i = 0; i < 4; ++i)
                #pragma unroll
                for (int j = 0; j < 4; ++j)
                    acc[i][j] = __builtin_amdgcn_mfma_f32_16x16x32_bf16(
                        af[i], bfr[j], acc[i][j], 0, 0, 0);
        }
        __syncthreads();
    }

    int cj[4]; float bvv[4]; bool okj[4];
    #pragma unroll
    for (int j = 0; j < 4; ++j) {
        cj[j] = bn0 + j * 16 + n16;
        okj[j] = cj[j] < V_SIZE;
        bvv[j] = okj[j] ? bias[cj[j]] : 0.f;
    }
    #pragma unroll
    for (int i = 0; i < 4; ++i) {
        const int r0 = wm + i * 16 + quad * 4;
        if (PART) {
            #pragma unroll
            for (int r = 0; r < 4; ++r) {
                float m = -1e30f;
                #pragma unroll
                for (int j = 0; j < 4; ++j)
                    if (okj[j]) m = fmaxf(m, acc[i][j][r] + bvv[j]);
                #pragma unroll
                for (int d = 1; d < 16; d <<= 1) m = fmaxf(m, __shfl_xor(m, d));
                float s = 0.f;
                #pragma unroll
                for (int j = 0; j < 4; ++j)
                    if (okj[j]) s += __expf(acc[i][j][r] + bvv[j] - m);
                #pragma unroll
                for (int d = 1; d < 16; d <<= 1) s += __shfl_xor(s, d);
                if (n16 == 0) {
                    pm[(size_t)blockIdx.x * B_SIZE + r0 + r] = m;
                    ps[(size_t)blockIdx.x * B_SIZE + r0 + r] = s;
                }
            }
        }
        #pragma unroll
        for (int j = 0; j < 4; ++j) if (okj[j]) {
            #pragma unroll
            for (int r = 0; r < 4; ++r)
                C[(size_t)(r0 + r) * V_SIZE + cj[j]] = acc[i][j][r] + bvv[j];
        }
    }
}

// ---------------------------------------------------------------------------
// K3c: GRU gate math (fp32), writes h_new (f32 to d_out) + bf16 copy for GEMM
// ---------------------------------------------------------------------------
__global__ __launch_bounds__(256) void gru_kernel(
    const float* __restrict__ gi, const float* __restrict__ gh,
    const float* __restrict__ hidden, float* __restrict__ hnew_out,
    unsigned short* __restrict__ hnew_bf)
{
    const int idx = blockIdx.x * 256 + threadIdx.x;   // < 131072
    const int b = idx >> 9, h = idx & 511;
    const float* gib = gi + (size_t)b * 3 * H_DIM;
    const float* ghb = gh + (size_t)b * 3 * H_DIM;
    float r = 1.f / (1.f + __expf(-(gib[h] + ghb[h])));
    float z = 1.f / (1.f + __expf(-(gib[H_DIM + h] + ghb[H_DIM + h])));
    float n = gib[2 * H_DIM + h] + r * ghb[2 * H_DIM + h];
    n = 1.f - 2.f / (1.f + __expf(2.f * n));          // tanh
    float hp = hidden[idx];
    float hn = (1.f - z) * n + z * hp;
    hnew_out[idx] = hn;
    hnew_bf[idx] = f2bf(hn);
}

// ---------------------------------------------------------------------------
// K5 (fallback only): combine partials -> lse, subtract over V-half.
// ---------------------------------------------------------------------------
__global__ __launch_bounds__(1024) void finalize_kernel(
    float* __restrict__ logits, const float* __restrict__ pm,
    const float* __restrict__ ps)
{
    const int b = blockIdx.x, tid = threadIdx.x;
    float m = -1e30f, s = 0.f;
    for (int i = tid; i < NBLK_LG; i += 1024) {
        float mm = pm[(size_t)i * B_SIZE + b], ss = ps[(size_t)i * B_SIZE + b];
        float nm = fmaxf(m, mm);
        s = s * __expf(m - nm) + ss * __expf(mm - nm);
        m = nm;
    }
    const int lane = tid & 63, wave = tid >> 6;
    #pragma unroll
    for (int off = 32; off; off >>= 1) {
        float m2 = __shfl_down(m, off), s2 = __shfl_down(s, off);
        float nm = fmaxf(m, m2);
        s = s * __expf(m - nm) + s2 * __expf(m2 - nm);
        m = nm;
    }
    __shared__ float msh[16], ssh[16], lse_sh;
    if (lane == 0) { msh[wave] = m; ssh[wave] = s; }
    __syncthreads();
    if (tid == 0) {
        float M = msh[0], S = ssh[0];
        for (int w = 1; w < 16; ++w) {
            float nm = fmaxf(M, msh[w]);
            S = S * __expf(M - nm) + ssh[w] * __expf(msh[w] - nm);
            M = nm;
        }
        lse_sh = M + logf(S);
    }
    __syncthreads();
    const float lse = lse_sh;
    constexpr int HALF = 25132;
    const int start = blockIdx.y * HALF;
    const int end = min(V_SIZE, start + HALF);
    float* row = logits + (size_t)b * V_SIZE;
    for (int c = start + tid; c < end; c += 1024) row[c] -= lse;
}

// fallback: two-pass log-softmax (only if ws too small for partials)
__global__ __launch_bounds__(1024) void logsoftmax_kernel(float* __restrict__ logits)
{
    const int b = blockIdx.x, tid = threadIdx.x;
    float* row = logits + (size_t)b * V_SIZE;
    float m = -1e30f, s = 0.f;
    for (int c = tid; c < V_SIZE; c += 1024) {
        float x = row[c];
        float nm = fmaxf(m, x);
        s = s * __expf(m - nm) + __expf(x - nm);
        m = nm;
    }
    const int lane = tid & 63, wave = tid >> 6;
    #pragma unroll
    for (int off = 32; off; off >>= 1) {
        float m2 = __shfl_down(m, off), s2 = __shfl_down(s, off);
        float nm = fmaxf(m, m2);
        s = s * __expf(m - nm) + s2 * __expf(m2 - nm);
        m = nm;
    }
    __shared__ float msh[16], ssh[16], lse_sh;
    if (lane == 0) { msh[wave] = m; ssh[wave] = s; }
    __syncthreads();
    if (tid == 0) {
        float M = msh[0], S = ssh[0];
        for (int w = 1; w < 16; ++w) {
            float nm = fmaxf(M, msh[w]);
            S = S * __expf(M - nm) + ssh[w] * __expf(msh[w] - nm);
            M = nm;
        }
        lse_sh = M + logf(S);
    }
    __syncthreads();
    const float lse = lse_sh;
    for (int c = tid; c < V_SIZE; c += 1024) row[c] -= lse;
}

// ---------------------------------------------------------------------------
// workspace layout (bytes)
// ---------------------------------------------------------------------------
constexpr size_t OFF_U      = 0;         // 256*512*4  = 524288
constexpr size_t OFF_XBF    = 524288;    // 256*1024*2 = 524288
constexpr size_t OFF_HBF    = 1048576;   // 256*512*2  = 262144
constexpr size_t OFF_HNEWBF = 1310720;   // 262144
constexpr size_t OFF_GI     = 1572864;   // 256*1536*4 = 1572864
constexpr size_t OFF_GH     = 3145728;   // 1572864
constexpr size_t OFF_PM     = 4718592;   // 786*256*4  = 804864
constexpr size_t OFF_PS     = 5523456;   // 804864
constexpr size_t OFF_LSE    = 6328320;   // 256*4 = 1024
constexpr size_t WS_NEED      = 6328320; // classic partials path
constexpr size_t WS_NEED_COOP = 6329344; // + lse

extern "C" void kernel_launch(void* const* d_in, const int* in_sizes, int n_in,
                              void* d_out, int out_size, void* d_ws, size_t ws_size,
                              hipStream_t stream) {
    const int*   tokens = (const int*)d_in[0];
    const float* hidden = (const float*)d_in[1];
    const float* enc    = (const float*)d_in[2];
    const float* emb    = (const float*)d_in[3];
    const float* attn_W = (const float*)d_in[4];
    // d_in[5] = attn_b: constant across s -> cancels in softmax; unused
    const float* W_ih   = (const float*)d_in[6];
    const float* W_hh   = (const float*)d_in[7];
    const float* b_ih   = (const float*)d_in[8];
    const float* b_hh   = (const float*)d_in[9];
    const float* out_W  = (const float*)d_in[10];
    const float* out_b  = (const float*)d_in[11];

    float* out = (float*)d_out;
    float* logp      = out;                                   // [256][50257]
    float* hnew_out  = out + (size_t)B_SIZE * V_SIZE;         // [256][512]
    float* attnw_out = hnew_out + (size_t)B_SIZE * H_DIM;     // [256][15]

    char* ws = (char*)d_ws;
    float*          u_ws    = (float*)(ws + OFF_U);
    unsigned short* x_bf    = (unsigned short*)(ws + OFF_XBF);
    unsigned short* h_bf    = (unsigned short*)(ws + OFF_HBF);
    unsigned short* hnew_bf = (unsigned short*)(ws + OFF_HNEWBF);
    float*          gi_ws   = (float*)(ws + OFF_GI);
    float*          gh_ws   = (float*)(ws + OFF_GH);
    float*          pm_ws   = (float*)(ws + OFF_PM);
    float*          ps_ws   = (float*)(ws + OFF_PS);
    float*          lse_ws  = (float*)(ws + OFF_LSE);

    u_kernel<<<dim3(16, 16), 256, 0, stream>>>(hidden, attn_W, u_ws);
    attn_kernel<<<dim3(256), 256, 0, stream>>>(hidden, enc, u_ws, tokens, emb,
                                               attnw_out, x_bf, h_bf);
    GemmP gi_p { x_bf, W_ih, b_ih, gi_ws, 3 * H_DIM, 2 * H_DIM };
    GemmP gh_p { h_bf, W_hh, b_hh, gh_ws, 3 * H_DIM, H_DIM };
    gemm_nt<64, 64, 64, 2, 2><<<dim3(24, 4, 2), 256, 0, stream>>>(gi_p, gh_p);
    gru_kernel<<<dim3(512), 256, 0, stream>>>(gi_ws, gh_ws, hidden, hnew_out, hnew_bf);

    bool done = false;
    if (ws_size >= WS_NEED_COOP) {
        const unsigned short* a_arg = hnew_bf;
        const float* b_arg = out_W;
        const float* bias_arg = out_b;
        float* c_arg = logp;
        float* pm_arg = pm_ws; float* ps_arg = ps_ws; float* lse_arg = lse_ws;
        void* args[7] = { &a_arg, &b_arg, &bias_arg, &c_arg,
                          &pm_arg, &ps_arg, &lse_arg };
        hipError_t e = hipLaunchCooperativeKernel(
            (const void*)gemm_lg_coop, dim3(NBLK_LG), dim3(256), args, 0, stream);
        done = (e == hipSuccess);
    }
    if (!done) {
        if (ws_size >= WS_NEED) {
            gemm_lg<true><<<dim3(NBLK_LG), 256, 0, stream>>>(
                hnew_bf, out_W, out_b, logp, pm_ws, ps_ws);
            finalize_kernel<<<dim3(256, 2), 1024, 0, stream>>>(logp, pm_ws, ps_ws);
        } else {
            gemm_lg<false><<<dim3(NBLK_LG), 256, 0, stream>>>(
                hnew_bf, out_W, out_b, logp, nullptr, nullptr);
            logsoftmax_kernel<<<dim3(256), 1024, 0, stream>>>(logp);
        }
    }
}

// Round 4
// 366.124 us; speedup vs baseline: 1.4936x; 1.4936x over previous
//
#include <hip/hip_runtime.h>

#define V_SIZE 50257
#define B_SIZE 256
#define S_LEN  15
#define H_DIM  512
#define NBLK_LG 786   // ceil(50257/64)

typedef __attribute__((ext_vector_type(8))) short bf16x8;
typedef __attribute__((ext_vector_type(4))) float f32x4;

__device__ __forceinline__ unsigned short f2bf(float f) {
    unsigned int u = __float_as_uint(f);
    u += 0x7fffu + ((u >> 16) & 1u);   // RNE
    return (unsigned short)(u >> 16);
}

// ---------------------------------------------------------------------------
// K1: u[b,n] = sum_o h[b,o] * attn_W[o,n]   (fp32 vector; 67 MMAC total)
// ---------------------------------------------------------------------------
__global__ __launch_bounds__(256) void u_kernel(
    const float* __restrict__ hidden, const float* __restrict__ attn_W,
    float* __restrict__ u)
{
    __shared__ float h_s[16][H_DIM];
    const int tid = threadIdx.x;
    const int b0 = blockIdx.y * 16, n0 = blockIdx.x * 32;
    const float4* hv = (const float4*)(hidden + (size_t)b0 * H_DIM);
    float4* hs4 = (float4*)&h_s[0][0];
    #pragma unroll
    for (int i = 0; i < 8; ++i) hs4[tid + i * 256] = hv[tid + i * 256];
    __syncthreads();
    const int n = n0 + (tid & 31);
    const int m = (tid >> 5) * 2;
    float a0 = 0.f, a1 = 0.f;
    #pragma unroll 8
    for (int o = 0; o < H_DIM; ++o) {
        float w = attn_W[(size_t)o * H_DIM + n];
        a0 += h_s[m][o] * w;
        a1 += h_s[m + 1][o] * w;
    }
    u[(size_t)(b0 + m) * H_DIM + n] = a0;
    u[(size_t)(b0 + m + 1) * H_DIM + n] = a1;
}

// ---------------------------------------------------------------------------
// K2: per-b attention + bf16 prep of x=[emb,ctx] and h (enc staged in LDS)
// ---------------------------------------------------------------------------
__global__ __launch_bounds__(256) void attn_kernel(
    const float* __restrict__ hidden, const float* __restrict__ enc,
    const float* __restrict__ u, const int* __restrict__ tokens,
    const float* __restrict__ emb, float* __restrict__ attnw_out,
    unsigned short* __restrict__ x_bf, unsigned short* __restrict__ h_bf)
{
    const int b = blockIdx.x, tid = threadIdx.x;
    __shared__ float e_s[S_LEN][H_DIM];   // 30720 B
    __shared__ float u_s[H_DIM];
    __shared__ float sc_s[S_LEN];
    __shared__ float w_s[S_LEN];
    {
        const float4* ev = (const float4*)(enc + (size_t)b * S_LEN * H_DIM);
        float4* es4 = (float4*)&e_s[0][0];
        #pragma unroll
        for (int i = 0; i < 8; ++i) {
            int idx = i * 256 + tid;
            if (idx < S_LEN * H_DIM / 4) es4[idx] = ev[idx];
        }
    }
    u_s[tid]       = u[(size_t)b * H_DIM + tid];
    u_s[tid + 256] = u[(size_t)b * H_DIM + tid + 256];
    h_bf[(size_t)b * H_DIM + tid]       = f2bf(hidden[(size_t)b * H_DIM + tid]);
    h_bf[(size_t)b * H_DIM + tid + 256] = f2bf(hidden[(size_t)b * H_DIM + tid + 256]);
    const int tok = tokens[b];
    x_bf[(size_t)b * 2 * H_DIM + tid]       = f2bf(emb[(size_t)tok * H_DIM + tid]);
    x_bf[(size_t)b * 2 * H_DIM + tid + 256] = f2bf(emb[(size_t)tok * H_DIM + tid + 256]);
    __syncthreads();
    const int wave = tid >> 6, lane = tid & 63;
    for (int s = wave; s < S_LEN; s += 4) {
        float acc = 0.f;
        #pragma unroll
        for (int k = 0; k < H_DIM / 64; ++k)
            acc += e_s[s][lane + k * 64] * u_s[lane + k * 64];
        #pragma unroll
        for (int off = 32; off; off >>= 1) acc += __shfl_down(acc, off);
        if (lane == 0) sc_s[s] = acc;
    }
    __syncthreads();
    float mx = -1e30f;
    for (int s = 0; s < S_LEN; ++s) mx = fmaxf(mx, sc_s[s]);
    float sum = 0.f;
    for (int s = 0; s < S_LEN; ++s) sum += __expf(sc_s[s] - mx);
    const float inv = 1.f / sum;
    if (tid < S_LEN) {
        float w = __expf(sc_s[tid] - mx) * inv;
        w_s[tid] = w;
        attnw_out[b * S_LEN + tid] = w;
    }
    __syncthreads();
    #pragma unroll
    for (int hh = 0; hh < 2; ++hh) {
        int h = tid + hh * 256;
        float c = 0.f;
        #pragma unroll
        for (int s = 0; s < S_LEN; ++s)
            c += w_s[s] * e_s[s][h];
        x_bf[(size_t)b * 2 * H_DIM + H_DIM + h] = f2bf(c);
    }
}

// ---------------------------------------------------------------------------
// Small NT MFMA GEMM: C = A(bf16) * B(f32->bf16)^T + bias
// ---------------------------------------------------------------------------
struct GemmP {
    const unsigned short* A; const float* B; const float* bias; float* C;
    int N; int K;
};

template<int BM, int BN, int BK, int WR, int WC>
__global__ __launch_bounds__(256) void gemm_nt(GemmP p0, GemmP p1)
{
    GemmP p = (blockIdx.z == 0) ? p0 : p1;
    constexpr int LDA = BK + 8;
    __shared__ __align__(16) unsigned short As[BM][LDA];
    __shared__ __align__(16) unsigned short Bs[BN][LDA];
    const int tid = threadIdx.x;
    const int bn0 = blockIdx.x * BN;
    const int bm0 = blockIdx.y * BM;
    const int wave = tid >> 6, lane = tid & 63;
    const int wm = (wave / WC) * (BM / WR);
    const int wn = (wave % WC) * (BN / WC);
    constexpr int MF = BM / WR / 16, NF = BN / WC / 16;
    const int n16 = lane & 15, quad = lane >> 4;

    f32x4 acc[MF][NF] = {};

    for (int k0 = 0; k0 < p.K; k0 += BK) {
        #pragma unroll
        for (int it = 0; it < BM / 32; ++it) {
            int v = it * 256 + tid;
            int row = v >> 3, seg = v & 7;
            *(uint4*)&As[row][seg * 8] =
                *(const uint4*)(p.A + (size_t)(bm0 + row) * p.K + k0 + seg * 8);
        }
        #pragma unroll
        for (int it = 0; it < BN / 32; ++it) {
            int v = it * 256 + tid;
            int row = v >> 3, seg = v & 7;
            int gv = bn0 + row;
            float4 w0 = make_float4(0, 0, 0, 0), w1 = make_float4(0, 0, 0, 0);
            if (gv < p.N) {
                const float4* src = (const float4*)(p.B + (size_t)gv * p.K + k0 + seg * 8);
                w0 = src[0]; w1 = src[1];
            }
            uint4 pk;
            pk.x = (unsigned)f2bf(w0.x) | ((unsigned)f2bf(w0.y) << 16);
            pk.y = (unsigned)f2bf(w0.z) | ((unsigned)f2bf(w0.w) << 16);
            pk.z = (unsigned)f2bf(w1.x) | ((unsigned)f2bf(w1.y) << 16);
            pk.w = (unsigned)f2bf(w1.z) | ((unsigned)f2bf(w1.w) << 16);
            *(uint4*)&Bs[row][seg * 8] = pk;
        }
        __syncthreads();
        #pragma unroll
        for (int kk = 0; kk < BK; kk += 32) {
            bf16x8 af[MF], bfr[NF];
            #pragma unroll
            for (int i = 0; i < MF; ++i)
                af[i] = *(const bf16x8*)&As[wm + i * 16 + n16][kk + quad * 8];
            #pragma unroll
            for (int j = 0; j < NF; ++j)
                bfr[j] = *(const bf16x8*)&Bs[wn + j * 16 + n16][kk + quad * 8];
            #pragma unroll
            for (int i = 0; i < MF; ++i)
                #pragma unroll
                for (int j = 0; j < NF; ++j)
                    acc[i][j] = __builtin_amdgcn_mfma_f32_16x16x32_bf16(
                        af[i], bfr[j], acc[i][j], 0, 0, 0);
        }
        __syncthreads();
    }
    #pragma unroll
    for (int i = 0; i < MF; ++i) {
        const int r0 = bm0 + wm + i * 16 + quad * 4;
        #pragma unroll
        for (int j = 0; j < NF; ++j) {
            const int c = bn0 + wn + j * 16 + n16;
            if (c < p.N) {
                const float bv = p.bias[c];
                #pragma unroll
                for (int r = 0; r < 4; ++r)
                    p.C[(size_t)(r0 + r) * p.N + c] = acc[i][j][r] + bv;
            }
        }
    }
}

// ---------------------------------------------------------------------------
// Logits GEMM: C[256, V] = hnew_bf[256,512] @ out_W[V,512]^T + out_b.
// R3 restructure: M-split for occupancy. Round-1 counters showed the 786-block
// grid itself capped occupancy at 28% (3.07 blocks/CU). Now BM=128, grid =
// 786 col-groups x 2 row-halves = 1572 blocks (~6.1/CU offered). Each wave
// owns 32 A-rows (acc[2][4] = 32 regs, halved accumulator pressure). The two
// row-halves of a col-group read the SAME B tile; the blk->(bx,by) decomposition
// below co-locates each pair on one XCD (ids differing by 8 share id%8) so the
// second read L2-hits instead of doubling HBM fetch.
// Partials layout pm[bx*256 + by*128 + r] == pm[bx*256 + globalrow]: identical
// to the old layout, zero workspace change.
// ---------------------------------------------------------------------------
template<bool PART>
__global__ __launch_bounds__(256, 4) void gemm_lg(
    const unsigned short* __restrict__ A, const float* __restrict__ B,
    const float* __restrict__ bias, float* __restrict__ C,
    float* __restrict__ pm, float* __restrict__ ps)
{
    constexpr int BN = 64, BK = 128;
    constexpr int LDB = BK + 8;              // 136 shorts = 272B pitch
    __shared__ __align__(16) unsigned short Bs[BN][LDB];
    const int tid = threadIdx.x;
    // co-XCD pair decomposition: ids g*16+s and g*16+s+8 share XCD (id%8)
    // and map to the same bx with by=0/1.
    const int blk = blockIdx.x;
    int bx, by;
    if (blk < 1568) { int g = blk >> 4, s = blk & 15; bx = g * 8 + (s & 7); by = s >> 3; }
    else            { int s = blk - 1568;             bx = 784 + (s >> 1);  by = s & 1;  }
    const int bn0 = bx * BN;
    const int m0  = by * 128;                 // this block's 128 A-rows
    const int wave = tid >> 6, lane = tid & 63;
    const int wm = wave * 32;                 // wave-private 32 A-rows
    const int n16 = lane & 15, quad = lane >> 4;

    f32x4 acc[2][4] = {};
    const unsigned short* arow[2];
    #pragma unroll
    for (int i = 0; i < 2; ++i)
        arow[i] = A + (size_t)(m0 + wm + i * 16 + n16) * H_DIM;

    for (int k0 = 0; k0 < H_DIM; k0 += BK) {
        // stage B: 64 rows x 128 k (f32) -> bf16 LDS. 1024 v-slots of 8 f32.
        #pragma unroll
        for (int it = 0; it < 4; ++it) {
            int v = it * 256 + tid;
            int row = v >> 4, seg = v & 15;
            int gv = bn0 + row;
            float4 w0 = make_float4(0, 0, 0, 0), w1 = make_float4(0, 0, 0, 0);
            if (gv < V_SIZE) {
                const float4* src = (const float4*)(B + (size_t)gv * H_DIM + k0 + seg * 8);
                w0 = src[0]; w1 = src[1];
            }
            uint4 pk;
            pk.x = (unsigned)f2bf(w0.x) | ((unsigned)f2bf(w0.y) << 16);
            pk.y = (unsigned)f2bf(w0.z) | ((unsigned)f2bf(w0.w) << 16);
            pk.z = (unsigned)f2bf(w1.x) | ((unsigned)f2bf(w1.y) << 16);
            pk.w = (unsigned)f2bf(w1.z) | ((unsigned)f2bf(w1.w) << 16);
            *(uint4*)&Bs[row][seg * 8] = pk;
        }
        __syncthreads();
        #pragma unroll
        for (int kk = 0; kk < BK; kk += 32) {
            bf16x8 af[2], bfr[4];
            #pragma unroll
            for (int i = 0; i < 2; ++i)
                af[i] = *(const bf16x8*)(arow[i] + k0 + kk + quad * 8);  // global, L2-hit
            #pragma unroll
            for (int j = 0; j < 4; ++j)
                bfr[j] = *(const bf16x8*)&Bs[j * 16 + n16][kk + quad * 8];
            #pragma unroll
            for (int i = 0; i < 2; ++i)
                #pragma unroll
                for (int j = 0; j < 4; ++j)
                    acc[i][j] = __builtin_amdgcn_mfma_f32_16x16x32_bf16(
                        af[i], bfr[j], acc[i][j], 0, 0, 0);
        }
        __syncthreads();
    }

    // epilogue
    int cj[4]; float bvv[4]; bool okj[4];
    #pragma unroll
    for (int j = 0; j < 4; ++j) {
        cj[j] = bn0 + j * 16 + n16;
        okj[j] = cj[j] < V_SIZE;
        bvv[j] = okj[j] ? bias[cj[j]] : 0.f;
    }
    #pragma unroll
    for (int i = 0; i < 2; ++i) {
        const int r0 = wm + i * 16 + quad * 4;         // local row in [0,128)
        if (PART) {
            #pragma unroll
            for (int r = 0; r < 4; ++r) {
                float m = -1e30f;
                #pragma unroll
                for (int j = 0; j < 4; ++j)
                    if (okj[j]) m = fmaxf(m, acc[i][j][r] + bvv[j]);
                #pragma unroll
                for (int d = 1; d < 16; d <<= 1) m = fmaxf(m, __shfl_xor(m, d));
                float s = 0.f;
                #pragma unroll
                for (int j = 0; j < 4; ++j)
                    if (okj[j]) s += __expf(acc[i][j][r] + bvv[j] - m);
                #pragma unroll
                for (int d = 1; d < 16; d <<= 1) s += __shfl_xor(s, d);
                if (n16 == 0) {
                    // pm[bx*256 + global_row]: same layout as before
                    pm[(size_t)bx * B_SIZE + m0 + r0 + r] = m;
                    ps[(size_t)bx * B_SIZE + m0 + r0 + r] = s;
                }
            }
        }
        #pragma unroll
        for (int j = 0; j < 4; ++j) if (okj[j]) {
            #pragma unroll
            for (int r = 0; r < 4; ++r)
                C[(size_t)(m0 + r0 + r) * V_SIZE + cj[j]] = acc[i][j][r] + bvv[j];
        }
    }
}

// ---------------------------------------------------------------------------
// K3c: GRU gate math (fp32), writes h_new (f32 to d_out) + bf16 copy for GEMM
// ---------------------------------------------------------------------------
__global__ __launch_bounds__(256) void gru_kernel(
    const float* __restrict__ gi, const float* __restrict__ gh,
    const float* __restrict__ hidden, float* __restrict__ hnew_out,
    unsigned short* __restrict__ hnew_bf)
{
    const int idx = blockIdx.x * 256 + threadIdx.x;   // < 131072
    const int b = idx >> 9, h = idx & 511;
    const float* gib = gi + (size_t)b * 3 * H_DIM;
    const float* ghb = gh + (size_t)b * 3 * H_DIM;
    float r = 1.f / (1.f + __expf(-(gib[h] + ghb[h])));
    float z = 1.f / (1.f + __expf(-(gib[H_DIM + h] + ghb[H_DIM + h])));
    float n = gib[2 * H_DIM + h] + r * ghb[2 * H_DIM + h];
    n = 1.f - 2.f / (1.f + __expf(2.f * n));          // tanh
    float hp = hidden[idx];
    float hn = (1.f - z) * n + z * hp;
    hnew_out[idx] = hn;
    hnew_bf[idx] = f2bf(hn);
}

// ---------------------------------------------------------------------------
// K5: combine 786 partials/row -> lse, subtract over this block's V-half.
// grid (256 rows, 2 halves), block 1024, float4-vectorized subtract.
// ---------------------------------------------------------------------------
__global__ __launch_bounds__(1024) void finalize_kernel(
    float* __restrict__ logits, const float* __restrict__ pm,
    const float* __restrict__ ps)
{
    const int b = blockIdx.x, tid = threadIdx.x;
    float m = -1e30f, s = 0.f;
    for (int i = tid; i < NBLK_LG; i += 1024) {
        float mm = pm[(size_t)i * B_SIZE + b], ss = ps[(size_t)i * B_SIZE + b];
        float nm = fmaxf(m, mm);
        s = s * __expf(m - nm) + ss * __expf(mm - nm);
        m = nm;
    }
    const int lane = tid & 63, wave = tid >> 6;
    #pragma unroll
    for (int off = 32; off; off >>= 1) {
        float m2 = __shfl_down(m, off), s2 = __shfl_down(s, off);
        float nm = fmaxf(m, m2);
        s = s * __expf(m - nm) + s2 * __expf(m2 - nm);
        m = nm;
    }
    __shared__ float msh[16], ssh[16], lse_sh;
    if (lane == 0) { msh[wave] = m; ssh[wave] = s; }
    __syncthreads();
    if (tid == 0) {
        float M = msh[0], S = ssh[0];
        for (int w = 1; w < 16; ++w) {
            float nm = fmaxf(M, msh[w]);
            S = S * __expf(M - nm) + ssh[w] * __expf(msh[w] - nm);
            M = nm;
        }
        lse_sh = M + logf(S);
    }
    __syncthreads();
    const float lse = lse_sh;
    constexpr int HALF = 25132;               // multiple of 4
    const int start = blockIdx.y * HALF;
    const int end = min(V_SIZE, start + HALF);
    float* p0 = logits + (size_t)b * V_SIZE + start;
    const int n = end - start;
    const int mis = (int)(((uintptr_t)p0 >> 2) & 3);
    int pre = mis ? (4 - mis) : 0; if (pre > n) pre = n;
    if (tid < pre) p0[tid] -= lse;
    const int nvec = (n - pre) >> 2;
    float4* rv = (float4*)(p0 + pre);
    for (int i = tid; i < nvec; i += 1024) {
        float4 v = rv[i];
        v.x -= lse; v.y -= lse; v.z -= lse; v.w -= lse;
        rv[i] = v;
    }
    const int rem = n - pre - (nvec << 2);
    if (tid < rem) p0[pre + (nvec << 2) + tid] -= lse;
}

// fallback: two-pass log-softmax (only if ws too small for partials)
__global__ __launch_bounds__(1024) void logsoftmax_kernel(float* __restrict__ logits)
{
    const int b = blockIdx.x, tid = threadIdx.x;
    float* row = logits + (size_t)b * V_SIZE;
    float m = -1e30f, s = 0.f;
    for (int c = tid; c < V_SIZE; c += 1024) {
        float x = row[c];
        float nm = fmaxf(m, x);
        s = s * __expf(m - nm) + __expf(x - nm);
        m = nm;
    }
    const int lane = tid & 63, wave = tid >> 6;
    #pragma unroll
    for (int off = 32; off; off >>= 1) {
        float m2 = __shfl_down(m, off), s2 = __shfl_down(s, off);
        float nm = fmaxf(m, m2);
        s = s * __expf(m - nm) + s2 * __expf(m2 - nm);
        m = nm;
    }
    __shared__ float msh[16], ssh[16], lse_sh;
    if (lane == 0) { msh[wave] = m; ssh[wave] = s; }
    __syncthreads();
    if (tid == 0) {
        float M = msh[0], S = ssh[0];
        for (int w = 1; w < 16; ++w) {
            float nm = fmaxf(M, msh[w]);
            S = S * __expf(M - nm) + ssh[w] * __expf(msh[w] - nm);
            M = nm;
        }
        lse_sh = M + logf(S);
    }
    __syncthreads();
    const float lse = lse_sh;
    for (int c = tid; c < V_SIZE; c += 1024) row[c] -= lse;
}

// ---------------------------------------------------------------------------
// workspace layout (bytes)
// ---------------------------------------------------------------------------
constexpr size_t OFF_U      = 0;         // 256*512*4  = 524288
constexpr size_t OFF_XBF    = 524288;    // 256*1024*2 = 524288
constexpr size_t OFF_HBF    = 1048576;   // 256*512*2  = 262144
constexpr size_t OFF_HNEWBF = 1310720;   // 262144
constexpr size_t OFF_GI     = 1572864;   // 256*1536*4 = 1572864
constexpr size_t OFF_GH     = 3145728;   // 1572864
constexpr size_t OFF_PM     = 4718592;   // 786*256*4  = 804864
constexpr size_t OFF_PS     = 5523456;   // 804864
constexpr size_t WS_NEED    = 6328320;

extern "C" void kernel_launch(void* const* d_in, const int* in_sizes, int n_in,
                              void* d_out, int out_size, void* d_ws, size_t ws_size,
                              hipStream_t stream) {
    const int*   tokens = (const int*)d_in[0];
    const float* hidden = (const float*)d_in[1];
    const float* enc    = (const float*)d_in[2];
    const float* emb    = (const float*)d_in[3];
    const float* attn_W = (const float*)d_in[4];
    // d_in[5] = attn_b: constant across s -> cancels in softmax; unused
    const float* W_ih   = (const float*)d_in[6];
    const float* W_hh   = (const float*)d_in[7];
    const float* b_ih   = (const float*)d_in[8];
    const float* b_hh   = (const float*)d_in[9];
    const float* out_W  = (const float*)d_in[10];
    const float* out_b  = (const float*)d_in[11];

    float* out = (float*)d_out;
    float* logp      = out;                                   // [256][50257]
    float* hnew_out  = out + (size_t)B_SIZE * V_SIZE;         // [256][512]
    float* attnw_out = hnew_out + (size_t)B_SIZE * H_DIM;     // [256][15]

    char* ws = (char*)d_ws;
    float*          u_ws    = (float*)(ws + OFF_U);
    unsigned short* x_bf    = (unsigned short*)(ws + OFF_XBF);
    unsigned short* h_bf    = (unsigned short*)(ws + OFF_HBF);
    unsigned short* hnew_bf = (unsigned short*)(ws + OFF_HNEWBF);
    float*          gi_ws   = (float*)(ws + OFF_GI);
    float*          gh_ws   = (float*)(ws + OFF_GH);
    float*          pm_ws   = (float*)(ws + OFF_PM);
    float*          ps_ws   = (float*)(ws + OFF_PS);

    u_kernel<<<dim3(16, 16), 256, 0, stream>>>(hidden, attn_W, u_ws);
    attn_kernel<<<dim3(256), 256, 0, stream>>>(hidden, enc, u_ws, tokens, emb,
                                               attnw_out, x_bf, h_bf);
    GemmP gi_p { x_bf, W_ih, b_ih, gi_ws, 3 * H_DIM, 2 * H_DIM };
    GemmP gh_p { h_bf, W_hh, b_hh, gh_ws, 3 * H_DIM, H_DIM };
    gemm_nt<64, 64, 64, 2, 2><<<dim3(24, 4, 2), 256, 0, stream>>>(gi_p, gh_p);
    gru_kernel<<<dim3(512), 256, 0, stream>>>(gi_ws, gh_ws, hidden, hnew_out, hnew_bf);

    if (ws_size >= WS_NEED) {
        gemm_lg<true><<<dim3(2 * NBLK_LG), 256, 0, stream>>>(
            hnew_bf, out_W, out_b, logp, pm_ws, ps_ws);
        finalize_kernel<<<dim3(256, 2), 1024, 0, stream>>>(logp, pm_ws, ps_ws);
    } else {
        gemm_lg<false><<<dim3(2 * NBLK_LG), 256, 0, stream>>>(
            hnew_bf, out_W, out_b, logp, nullptr, nullptr);
        logsoftmax_kernel<<<dim3(256), 1024, 0, stream>>>(logp);
    }
}